// Round 1
// 183.340 us; speedup vs baseline: 1.0147x; 1.0147x over previous
//
#include <hip/hip_runtime.h>

// PlanarQuantMSE: per-row normalize -> per-pair 2x2 rotate -> 16-centroid
// nearest quantize -> dequant -> inverse rotate -> rescale.
// B=4096, d=4096, n_groups=2048, 16 sorted centroids.
//
// R7: top-5 rocprof rows are all harness poison fills (~80us each); kernel
// <79us, est 36-56us vs ~28us streaming floor. R5->R6 showed LDS count and
// phase-2 load latency are not the limiter. Remaining theory: occupancy.
// R6 held xa[4]+ra[4] (32 VGPRs) live across the norm barrier -> ~100+ VGPR
// -> 4 waves/SIMD (occupancy halves at 64/128 VGPR). This round stashes the
// row in LDS (16 KB, under the 8-block/CU wave cap) so only the fp64 partial
// sum survives the barrier, and drops the rot2 register prefetch (rot2 is
// L1/L2-hot: every block reads the same 16 KB). Target: <=64 VGPR -> 8
// waves/SIMD -> phase-2 store stream fully latency-hidden.
// Math is bit-identical to R6 (same fp64 norm accumulation order, same fp32
// scan + fp64 midpoint fallback), so absmax stays at 0.125.

#define ROW_D     4096
#define BLOCK_T   256
#define F4_PER_T  4   // (ROW_D/4)/BLOCK_T

typedef float f32x4 __attribute__((ext_vector_type(4)));

struct QP { float o0, o1, i0, i1; };

__device__ __forceinline__ QP quant_pair(
    float x0, float x1, float c, float s,
    float invf, float dnf, double invd,
    const float* __restrict__ mf,            // 15 fp32 midpoints (regs/SGPR)
    const float4* __restrict__ w4,           // LDS: (md[k-1], cd[k], md[k], 0)
    const float* __restrict__ cent)          // global centroids (fp64 fallback)
{
    // fp32 fast path: rotate
    const float v0 = x0 * invf, v1 = x1 * invf;
    const float r0 = c * v0 - s * v1;
    const float r1 = s * v0 + c * v1;

    // count-only scan: a = #{j : r > md[j]}  (== argmin over sorted centroids,
    // first-min tie-break since '>' keeps the lower index at exact midpoints)
    int a = 0, b = 0;
#pragma unroll
    for (int j = 0; j < 15; ++j) {
        a += (r0 > mf[j]) ? 1 : 0;
        b += (r1 > mf[j]) ? 1 : 0;
    }

    // one b128 lookup per value: lower bound, centroid, upper bound
    const float4 pa = w4[a];
    const float4 pb = w4[b];
    float q0 = pa.y, q1 = pb.y;

    // near-tie guard: distance to the chosen interval's boundaries
    const float EPS = 1e-5f;
    const float g0 = fminf(r0 - pa.x, pa.z - r0);
    const float g1 = fminf(r1 - pb.x, pb.z - r1);
    if (g0 < EPS || g1 < EPS) {
        // fp64 recompute for this pair (rare, exec-masked)
        const double v0d = (double)x0 * invd;
        const double v1d = (double)x1 * invd;
        const double cd = (double)c, sd = (double)s;
        const double r0d = cd * v0d - sd * v1d;
        const double r1d = sd * v0d + cd * v1d;
        a = 0; b = 0;
        double q0d = (double)cent[0], q1d = (double)cent[0];
#pragma unroll
        for (int j = 0; j < 15; ++j) {
            const double mj = 0.5 * ((double)cent[j] + (double)cent[j + 1]);  // exact
            const bool ca = r0d > mj;
            const bool cb = r1d > mj;
            a += ca ? 1 : 0;
            b += cb ? 1 : 0;
            q0d = ca ? (double)cent[j + 1] : q0d;
            q1d = cb ? (double)cent[j + 1] : q1d;
        }
        q0 = (float)q0d;
        q1 = (float)q1d;
    }

    // dequant + inverse rotate + rescale (comparison is bf16-granular)
    QP r;
    r.o0 = (c * q0 + s * q1) * dnf;
    r.o1 = (c * q1 - s * q0) * dnf;
    r.i0 = (float)a;
    r.i1 = (float)b;
    return r;
}

__global__ __launch_bounds__(BLOCK_T) void planar_quant_kernel(
    const float* __restrict__ x,
    const float* __restrict__ cent,
    const float* __restrict__ rot2,
    float* __restrict__ out_xhat,
    float* __restrict__ out_idx)
{
    const int row = blockIdx.x;
    const int t   = threadIdx.x;

    const f32x4* xr = (const f32x4*)(x + (size_t)row * ROW_D);
    const float4* rr = (const float4*)rot2;   // float4 f covers pairs 2f, 2f+1

    __shared__ f32x4  xs[ROW_D / 4];   // 16 KB row stash: frees 32 VGPRs
    __shared__ double smem[5];
    __shared__ float4 w4[16];          // (md[k-1], cd[k], md[k], 0); ends = +-inf

    // Phase 1: stream row -> LDS (nontemporal global read: read-once),
    // fp64 sum of squares. Only `ss` lives across the barrier.
    double ss = 0.0;
#pragma unroll
    for (int i = 0; i < F4_PER_T; ++i) {
        f32x4 v = __builtin_nontemporal_load(&xr[t + BLOCK_T * i]);
        xs[t + BLOCK_T * i] = v;
        ss += (double)v.x * (double)v.x;
        ss += (double)v.y * (double)v.y;
        ss += (double)v.z * (double)v.z;
        ss += (double)v.w * (double)v.w;
    }

#pragma unroll
    for (int off = 32; off > 0; off >>= 1)
        ss += __shfl_down(ss, off, 64);

    const int wid = t >> 6;
    if ((t & 63) == 0) smem[wid] = ss;

    // centroids + midpoints in fp32 (uniform loads -> scalar regs)
    float cf[16];
#pragma unroll
    for (int j = 0; j < 16; ++j) cf[j] = cent[j];
    float mf[15];
#pragma unroll
    for (int j = 0; j < 15; ++j) mf[j] = 0.5f * (cf[j] + cf[j + 1]);

    if (t < 16) {
        const float lo = (t == 0)  ? -3.0e38f : 0.5f * (cf[t - 1] + cf[t]);
        const float hi = (t == 15) ?  3.0e38f : 0.5f * (cf[t] + cf[t + 1]);
        w4[t] = make_float4(lo, cf[t], hi, 0.0f);
    }
    __syncthreads();
    if (t == 0) {
        double tot = smem[0] + smem[1] + smem[2] + smem[3];
        double n = sqrt(tot);
        smem[4] = (n < 1e-8) ? 1e-8 : n;   // jnp.clip(norm, 1e-8)
    }
    __syncthreads();
    const double dnd  = smem[4];
    const double invd = 1.0 / dnd;
    const float  dnf  = (float)dnd;
    const float  invf = (float)invd;

    f32x4* xo = (f32x4*)(out_xhat + (size_t)row * ROW_D);
    f32x4* io = (f32x4*)(out_idx  + (size_t)row * ROW_D);

    // Phase 2: reload row from LDS (conflict-free b128), rot2 from L1/L2;
    // rotate/quantize/dequantize; nontemporal coalesced stores.
#pragma unroll
    for (int i = 0; i < F4_PER_T; ++i) {
        const int f = t + BLOCK_T * i;
        const f32x4 xv = xs[f];
        const float4 rv = rr[f];
        const QP lo = quant_pair(xv.x, xv.y, rv.x, rv.y, invf, dnf, invd, mf, w4, cent);
        const QP hi = quant_pair(xv.z, xv.w, rv.z, rv.w, invf, dnf, invd, mf, w4, cent);
        f32x4 ov, iv;
        ov.x = lo.o0; ov.y = lo.o1; ov.z = hi.o0; ov.w = hi.o1;
        iv.x = lo.i0; iv.y = lo.i1; iv.z = hi.i0; iv.w = hi.i1;
        __builtin_nontemporal_store(ov, &xo[f]);
        __builtin_nontemporal_store(iv, &io[f]);
    }
}

extern "C" void kernel_launch(void* const* d_in, const int* in_sizes, int n_in,
                              void* d_out, int out_size, void* d_ws, size_t ws_size,
                              hipStream_t stream) {
    const float* x    = (const float*)d_in[0];
    const float* cent = (const float*)d_in[1];
    const float* rot2 = (const float*)d_in[2];

    const int d = in_sizes[2];           // 2*n_groups = 4096
    const int B = in_sizes[0] / d;       // 4096

    float* out  = (float*)d_out;
    float* xhat = out;                   // output 0: x_hat (B*d fp32)
    float* idxo = out + (size_t)B * d;   // output 1: indices as fp32 values

    planar_quant_kernel<<<B, BLOCK_T, 0, stream>>>(x, cent, rot2, xhat, idxo);
}